// Round 1
// baseline (226.625 us; speedup 1.0000x reference)
//
#include <hip/hip_runtime.h>
#include <math.h>

// Problem constants
constexpr int B_ = 4, C_ = 192, N_ = 160, M_ = 160;
constexpr int NM_ = N_ * M_;            // 25600
constexpr float SQRT_C = 13.856406460551018f;   // sqrt(192)
constexpr float SCALE_ = 0.17677669529663687f;  // 1/sqrt(32)

__device__ __forceinline__ float wred_sum(float v) {
    #pragma unroll
    for (int o = 32; o > 0; o >>= 1) v += __shfl_xor(v, o, 64);
    return v;
}
__device__ __forceinline__ float wred_max(float v) {
    #pragma unroll
    for (int o = 32; o > 0; o >>= 1) v = fmaxf(v, __shfl_xor(v, o, 64));
    return v;
}

// K1 (fused): blocks 0..399    -> rn[b,n,m] = sqrt(C)/max(||x[b,:,n,m]||,1e-12) (full 192-c ssq)
//             blocks 400..591  -> WfT2[pair*128+hd] = sum_c Wr[dch,t*192+c]*Wo[c,hd]; bfb
//             blocks 592..879  -> WT[mat][hd*192+c] = g[c]*W[hd*192+c]  (natural layout, g folded)
__global__ __launch_bounds__(256) void prep_rn_kernel(
        const float* __restrict__ x,
        const float* __restrict__ Wr, const float* __restrict__ Wo,
        const float* __restrict__ bo,
        const float* __restrict__ Wq, const float* __restrict__ Wk,
        const float* __restrict__ Wv, const float* __restrict__ gq,
        const float* __restrict__ gk, const float* __restrict__ gv,
        float* __restrict__ rn, float* __restrict__ WfT2,
        float* __restrict__ bfb, float* __restrict__ WT) {
    int bx = blockIdx.x, tid = threadIdx.x;
    if (bx < 400) {
        int g = bx * 256 + tid;              // [0, 102400) = b*NM + nm
        int b = g / NM_, nm = g - b * NM_;
        const float* xp = x + (size_t)b * (C_ * NM_) + nm;
        float s = 0.f;
        #pragma unroll 16
        for (int c = 0; c < C_; c++) { float v = xp[(size_t)c * NM_]; s += v * v; }
        rn[g] = SQRT_C / fmaxf(sqrtf(s), 1e-12f);
    } else if (bx < 592) {
        int pair = (bx - 400) * 2 + (tid >> 7);   // t*192 + dch in [0,384)
        int hd = tid & 127;
        int t = pair / 192, dch = pair % 192;
        const float* wr = Wr + dch * 384 + t * 192;
        float acc = 0.f;
        for (int c = 0; c < 192; c++) acc += wr[c] * Wo[c * 128 + hd];
        WfT2[pair * 128 + hd] = acc;
        if (hd == 0) {
            float sb = 0.f;
            for (int c = 0; c < 192; c++) sb += wr[c] * bo[c];
            bfb[pair] = sb;
        }
    } else {
        int g = (bx - 592) * 256 + tid;      // < 73728
        int mat = g / 24576, r2 = g - mat * 24576;   // r2 = hd*192 + c
        const float* W  = (mat == 0) ? Wq : ((mat == 1) ? Wk : Wv);
        const float* gp = (mat == 0) ? gq : ((mat == 1) ? gk : gv);
        WT[g] = gp[r2 % 192] * W[r2];
    }
}

// K23: per (b,c) plane: rowft/Srow (reduce over m), colft/Scol (reduce over n).
__global__ __launch_bounds__(512) void rowcol_kernel(
        const float* __restrict__ x, const float* __restrict__ rn,
        float* __restrict__ rowft, float* __restrict__ colft,
        float* __restrict__ Srow, float* __restrict__ Scol) {
    __shared__ float cpart[8][2][160];
    int bc = blockIdx.x;                 // b*192 + c
    int b = bc / C_;
    int tid = threadIdx.x, w = tid >> 6, lane = tid & 63;
    const float* xp = x + (size_t)bc * NM_;
    const float* rp = rn + (size_t)b * NM_;
    int m0 = lane, m1 = lane + 64, m2 = lane + 128;
    bool ok2 = (m2 < M_);
    float cr0 = 0, cr1 = 0, cr2 = 0, cn0 = 0, cn1 = 0, cn2 = 0;
    for (int n = w; n < N_; n += 8) {
        const float* xr = xp + n * M_;
        const float* rr = rp + n * M_;
        float a0 = xr[m0], a1 = xr[m1], a2 = ok2 ? xr[m2] : 0.f;
        float r0 = rr[m0], r1 = rr[m1], r2 = ok2 ? rr[m2] : 0.f;
        float b0 = a0 * r0, b1 = a1 * r1, b2 = a2 * r2;
        cr0 += a0; cr1 += a1; cr2 += a2;
        cn0 += b0; cn1 += b1; cn2 += b2;
        float rs = wred_sum(a0 + a1 + a2);
        float rsn = wred_sum(b0 + b1 + b2);
        if (lane == 0) {
            rowft[bc * N_ + n] = rs * (1.0f / 160.0f);
            Srow[bc * N_ + n] = rsn;
        }
    }
    cpart[w][0][m0] = cr0; cpart[w][0][m1] = cr1; if (ok2) cpart[w][0][m2] = cr2;
    cpart[w][1][m0] = cn0; cpart[w][1][m1] = cn1; if (ok2) cpart[w][1][m2] = cn2;
    __syncthreads();
    if (tid < M_) {
        float sr = 0.f, sn = 0.f;
        #pragma unroll
        for (int ww = 0; ww < 8; ww++) { sr += cpart[ww][0][tid]; sn += cpart[ww][1][tid]; }
        colft[bc * M_ + tid] = sr * (1.0f / 160.0f);
        Scol[bc * M_ + tid] = sn;
    }
}

// K4b: Q/K/Vsum projections, fused per-position RMS (g pre-folded into WT).
// in_s transposed [p][196] so the GEMM reads float4 along c; WT natural [hd][c].
__global__ __launch_bounds__(256) void proj_kernel(
        const float* __restrict__ WT,
        const float* __restrict__ rowft, const float* __restrict__ colft,
        const float* __restrict__ Srow, const float* __restrict__ Scol,
        float* __restrict__ Qb, float* __restrict__ Kb, float* __restrict__ Vb) {
    __shared__ float in_s[4 * 196];
    __shared__ float sc_s[4];
    int bx = blockIdx.x;
    int pt = bx % 40, rest = bx / 40;
    int mat = rest % 3; int r2 = rest / 3;
    int t = r2 % 2, b = r2 / 2;
    const float* src; float* dst;
    if (mat == 0)      { src = (t == 0) ? rowft : colft; dst = Qb; }
    else if (mat == 1) { src = (t == 0) ? colft : rowft; dst = Kb; }
    else               { src = (t == 0) ? Scol  : Srow;  dst = Vb; }
    const float* Wt = WT + mat * 24576;
    int tid = threadIdx.x;
    for (int idx = tid; idx < 768; idx += 256) {
        int c = idx >> 2, p = idx & 3;
        in_s[p * 196 + c] = src[(b * C_ + c) * 160 + pt * 4 + p];
    }
    __syncthreads();
    int w = tid >> 6, lane = tid & 63;
    if (mat < 2) {
        float v0 = in_s[w * 196 + lane];
        float v1 = in_s[w * 196 + lane + 64];
        float v2 = in_s[w * 196 + lane + 128];
        float ssq = wred_sum(v0 * v0 + v1 * v1 + v2 * v2);
        if (lane == 0) sc_s[w] = SQRT_C / fmaxf(sqrtf(ssq), 1e-12f);
    } else {
        if (tid < 4) sc_s[tid] = 1.0f;
    }
    __syncthreads();
    int hd = tid & 127, p0 = (tid >> 7) * 2;
    const float* wp = Wt + hd * 192;
    const float* i0p = &in_s[p0 * 196];
    const float* i1p = &in_s[(p0 + 1) * 196];
    float a0 = 0.f, a1 = 0.f;
    #pragma unroll 4
    for (int c0 = 0; c0 < 192; c0 += 4) {
        float4 wv = *reinterpret_cast<const float4*>(wp + c0);
        float4 u0 = *reinterpret_cast<const float4*>(i0p + c0);
        float4 u1 = *reinterpret_cast<const float4*>(i1p + c0);
        a0 += wv.x * u0.x + wv.y * u0.y + wv.z * u0.z + wv.w * u0.w;
        a1 += wv.x * u1.x + wv.y * u1.y + wv.z * u1.z + wv.w * u1.w;
    }
    int posbase = (b * 2 + t) * 160 + pt * 4 + p0;
    dst[(size_t)posbase * 128 + hd]       = a0 * sc_s[p0];
    dst[(size_t)(posbase + 1) * 128 + hd] = a1 * sc_s[p0 + 1];
}

// K4c: attention. grid 640 = (b,t,h)*20 q-tiles of 8, block 256 (4 waves x 2 queries).
// K in [key][36] (aligned float4 rows), V transposed [d][172] (float4 along key).
__global__ __launch_bounds__(256) void attn_kernel(
        const float* __restrict__ Qb, const float* __restrict__ Kb,
        const float* __restrict__ Vb, const float* __restrict__ memkv,
        float* __restrict__ AO) {
    __shared__ float k_s[160 * 36];
    __shared__ float v_s[32 * 172];
    __shared__ float q_s[8 * 36];
    __shared__ float e_s[8 * 160];
    __shared__ float mk[128];
    __shared__ float mv[128];
    int bx = blockIdx.x;
    int qt = bx % 20; int r = bx / 20;
    int h = r & 3; r >>= 2;
    int t = r & 1; int b = r >> 1;
    int tid = threadIdx.x, w = tid >> 6, lane = tid & 63;
    int btbase = ((b * 2 + t) * 160) * 128 + h * 32;
    for (int idx = tid; idx < 1280; idx += 256) {
        int k = idx >> 3, dq = idx & 7;
        float4 kv = *reinterpret_cast<const float4*>(Kb + btbase + k * 128 + dq * 4);
        *reinterpret_cast<float4*>(&k_s[k * 36 + dq * 4]) = kv;
        float4 vv = *reinterpret_cast<const float4*>(Vb + btbase + k * 128 + dq * 4);
        v_s[(dq * 4 + 0) * 172 + k] = vv.x;
        v_s[(dq * 4 + 1) * 172 + k] = vv.y;
        v_s[(dq * 4 + 2) * 172 + k] = vv.z;
        v_s[(dq * 4 + 3) * 172 + k] = vv.w;
    }
    if (tid < 64) {
        int q = tid >> 3, dq = tid & 7;
        *reinterpret_cast<float4*>(&q_s[q * 36 + dq * 4]) =
            *reinterpret_cast<const float4*>(Qb + btbase + (qt * 8 + q) * 128 + dq * 4);
    }
    if (tid < 128) {
        mk[tid] = memkv[h * 128 + tid];
        mv[tid] = memkv[512 + h * 128 + tid];
    }
    __syncthreads();
    float4 kr0[8], kr1[8], kr2[8];
    #pragma unroll
    for (int dq = 0; dq < 8; dq++) {
        kr0[dq] = *reinterpret_cast<const float4*>(&k_s[lane * 36 + dq * 4]);
        kr1[dq] = *reinterpret_cast<const float4*>(&k_s[(lane + 64) * 36 + dq * 4]);
        if (lane < 32) kr2[dq] = *reinterpret_cast<const float4*>(&k_s[(lane + 128) * 36 + dq * 4]);
        else           kr2[dq] = make_float4(0.f, 0.f, 0.f, 0.f);
    }
    float p;
    {
        int pj = lane >> 3, qi = pj >> 2, j = pj & 3;
        int db = (lane & 7) * 4;
        float4 qv = *reinterpret_cast<const float4*>(&q_s[(w * 2 + qi) * 36 + db]);
        float4 mkv = *reinterpret_cast<const float4*>(&mk[j * 32 + db]);
        p = qv.x * mkv.x + qv.y * mkv.y + qv.z * mkv.z + qv.w * mkv.w;
        p += __shfl_xor(p, 1, 64); p += __shfl_xor(p, 2, 64); p += __shfl_xor(p, 4, 64);
        p *= SCALE_;
    }
    float sm[2][4];
    #pragma unroll
    for (int j = 0; j < 4; j++) {
        sm[0][j] = __shfl(p, j * 8, 64);
        sm[1][j] = __shfl(p, 32 + j * 8, 64);
    }
    int dpv = lane & 31;
    float Zq[2], accm[2];
    #pragma unroll
    for (int qi = 0; qi < 2; qi++) {
        const float* qrow = &q_s[(w * 2 + qi) * 36];
        float s0 = 0.f, s1 = 0.f, s2 = 0.f;
        #pragma unroll
        for (int dq = 0; dq < 8; dq++) {
            float4 qv = *reinterpret_cast<const float4*>(qrow + dq * 4);
            s0 += qv.x * kr0[dq].x + qv.y * kr0[dq].y + qv.z * kr0[dq].z + qv.w * kr0[dq].w;
            s1 += qv.x * kr1[dq].x + qv.y * kr1[dq].y + qv.z * kr1[dq].z + qv.w * kr1[dq].w;
            s2 += qv.x * kr2[dq].x + qv.y * kr2[dq].y + qv.z * kr2[dq].z + qv.w * kr2[dq].w;
        }
        s0 *= SCALE_; s1 *= SCALE_;
        s2 = (lane < 32) ? s2 * SCALE_ : -1e30f;
        float mx = fmaxf(fmaxf(s0, s1), s2);
        mx = fmaxf(mx, fmaxf(fmaxf(sm[qi][0], sm[qi][1]), fmaxf(sm[qi][2], sm[qi][3])));
        mx = wred_max(mx);
        float e0 = __expf(s0 - mx), e1 = __expf(s1 - mx);
        float e2 = (lane < 32) ? __expf(s2 - mx) : 0.f;
        int eb = (w * 2 + qi) * 160;
        e_s[eb + lane] = e0; e_s[eb + 64 + lane] = e1;
        if (lane < 32) e_s[eb + 128 + lane] = e2;
        float esum = wred_sum(e0 + e1 + e2);
        float em0 = __expf(sm[qi][0] - mx), em1 = __expf(sm[qi][1] - mx);
        float em2 = __expf(sm[qi][2] - mx), em3 = __expf(sm[qi][3] - mx);
        Zq[qi] = (em0 + em1 + em2 + em3) + 160.0f * esum;
        accm[qi] = em0 * mv[dpv] + em1 * mv[32 + dpv] + em2 * mv[64 + dpv] + em3 * mv[96 + dpv];
    }
    int half = lane >> 5, k0 = half * 80;
    const float* vrow = &v_s[dpv * 172 + k0];
    const float* e0p = &e_s[(w * 2) * 160 + k0];
    const float* e1p = &e_s[(w * 2 + 1) * 160 + k0];
    float a0 = 0.f, a1 = 0.f;
    #pragma unroll 4
    for (int kk = 0; kk < 80; kk += 4) {
        float4 vv = *reinterpret_cast<const float4*>(vrow + kk);
        float4 e0 = *reinterpret_cast<const float4*>(e0p + kk);
        float4 e1 = *reinterpret_cast<const float4*>(e1p + kk);
        a0 += e0.x * vv.x + e0.y * vv.y + e0.z * vv.z + e0.w * vv.w;
        a1 += e1.x * vv.x + e1.y * vv.y + e1.z * vv.z + e1.w * vv.w;
    }
    a0 += __shfl_down(a0, 32, 64);
    a1 += __shfl_down(a1, 32, 64);
    if (lane < 32) {
        AO[btbase + (qt * 8 + w * 2 + 0) * 128 + lane] = (accm[0] + a0) / Zq[0];
        AO[btbase + (qt * 8 + w * 2 + 1) * 128 + lane] = (accm[1] + a1) / Zq[1];
    }
}

// K4d: fused (Wr@Wo) projection; WfT2 in [pair][hd] so inner loop is float4 over hd.
__global__ __launch_bounds__(192) void oproj_kernel(
        const float* __restrict__ WfT2, const float* __restrict__ bfb,
        const float* __restrict__ AO, float* __restrict__ Rr,
        float* __restrict__ Ccv) {
    __shared__ float ao_s[2 * 128];
    int bx = blockIdx.x;
    int pt = bx % 80, rest = bx / 80;
    int t = rest & 1, b = rest >> 1;
    int tid = threadIdx.x;  // 192
    for (int idx = tid; idx < 256; idx += 192)
        ao_s[idx] = AO[(size_t)((b * 2 + t) * 160 + pt * 2 + (idx >> 7)) * 128 + (idx & 127)];
    __syncthreads();
    int tofs = t * 192 + tid;
    const float* wp = WfT2 + tofs * 128;
    float a0 = 0.f, a1 = 0.f;
    #pragma unroll 8
    for (int hd = 0; hd < 128; hd += 4) {
        float4 w4 = *reinterpret_cast<const float4*>(wp + hd);
        float4 x0 = *reinterpret_cast<const float4*>(&ao_s[hd]);
        float4 x1 = *reinterpret_cast<const float4*>(&ao_s[128 + hd]);
        a0 += w4.x * x0.x + w4.y * x0.y + w4.z * x0.z + w4.w * x0.w;
        a1 += w4.x * x1.x + w4.y * x1.y + w4.z * x1.z + w4.w * x1.w;
    }
    float bb = bfb[tofs];
    float* dst = t ? Ccv : Rr;
    dst[(b * C_ + tid) * 160 + pt * 2 + 0] = a0 + bb;
    dst[(b * C_ + tid) * 160 + pt * 2 + 1] = a1 + bb;
}

// K5: out[b,d,n,m] = R[b,d,n] + C[b,d,m].  grid 768, block 256, float4 stores
__global__ __launch_bounds__(256) void final_kernel(
        const float* __restrict__ Rr, const float* __restrict__ Ccv,
        float* __restrict__ out) {
    __shared__ float Rl[160];
    __shared__ float Cl[160];
    int bd = blockIdx.x;
    int tid = threadIdx.x;
    if (tid < 160) { Rl[tid] = Rr[bd * 160 + tid]; Cl[tid] = Ccv[bd * 160 + tid]; }
    __syncthreads();
    float* base = out + (size_t)bd * NM_;
    for (int idx = tid; idx < 160 * 40; idx += 256) {
        int n = idx / 40, m4 = idx - n * 40;
        float r = Rl[n];
        float4 v;
        v.x = r + Cl[m4 * 4 + 0];
        v.y = r + Cl[m4 * 4 + 1];
        v.z = r + Cl[m4 * 4 + 2];
        v.w = r + Cl[m4 * 4 + 3];
        *reinterpret_cast<float4*>(base + n * 160 + m4 * 4) = v;
    }
}

extern "C" void kernel_launch(void* const* d_in, const int* in_sizes, int n_in,
                              void* d_out, int out_size, void* d_ws, size_t ws_size,
                              hipStream_t stream) {
    const float* x    = (const float*)d_in[0];
    const float* gq   = (const float*)d_in[1];
    const float* gk   = (const float*)d_in[2];
    const float* gv   = (const float*)d_in[3];
    const float* Wq   = (const float*)d_in[4];
    const float* Wk   = (const float*)d_in[5];
    const float* Wv   = (const float*)d_in[6];
    const float* mkv  = (const float*)d_in[7];
    const float* Wo   = (const float*)d_in[8];
    const float* bo   = (const float*)d_in[9];
    const float* Wr   = (const float*)d_in[10];
    float* out = (float*)d_out;

    float* ws = (float*)d_ws;
    float* rn    = ws;                  // 102400
    float* rowft = rn    + 102400;      // 122880
    float* colft = rowft + 122880;
    float* Srow  = colft + 122880;
    float* Scol  = Srow  + 122880;
    float* WT    = Scol  + 122880;      // 73728 (g-folded Wq/Wk/Wv, natural [hd][c])
    float* Qb    = WT    + 73728;       // 163840
    float* Kb    = Qb    + 163840;
    float* Vb    = Kb    + 163840;
    float* AO    = Vb    + 163840;      // 163840
    float* Rr    = AO    + 163840;      // 122880
    float* Ccv   = Rr    + 122880;
    float* WfT   = Ccv   + 122880;      // 49152 ([pair][hd] layout)
    float* bfb   = WfT   + 49152;       // 384

    prep_rn_kernel<<<880, 256, 0, stream>>>(x, Wr, Wo, bo, Wq, Wk, Wv, gq, gk, gv,
                                            rn, WfT, bfb, WT);
    rowcol_kernel<<<768, 512, 0, stream>>>(x, rn, rowft, colft, Srow, Scol);
    proj_kernel<<<960, 256, 0, stream>>>(WT, rowft, colft, Srow, Scol, Qb, Kb, Vb);
    attn_kernel<<<640, 256, 0, stream>>>(Qb, Kb, Vb, mkv, AO);
    oproj_kernel<<<640, 192, 0, stream>>>(WfT, bfb, AO, Rr, Ccv);
    final_kernel<<<768, 256, 0, stream>>>(Rr, Ccv, out);
}